// Round 2
// baseline (875.530 us; speedup 1.0000x reference)
//
#include <hip/hip_runtime.h>
#include <stdint.h>
#include <math.h>

#define NUM_CLASSES 21
#define TOPK 200
#define P_NUM 120000
#define B_NUM 8
#define NBINS 4096
#define CAP 2048
#define PRE_TH 0.99f
#define CONF_TH 0.05f
#define NMS_TH 0.3f
#define RPB 512               // rows per prefilter block

// ws layout: [0..672) counters (168 ints), [1024 ..) cand_g: 168 * CAP u64
#define CAND_OFF 1024

// ---------------------------------------------------------------------------
// Kernel 1: wide prefilter. Collect all scores > PRE_TH into per-(b,c) global
// buffers. Exact top-200 coverage is guaranteed whenever count >= TOPK
// (checked in kernel 2; falls back to full scan otherwise).
// ---------------------------------------------------------------------------
__global__ __launch_bounds__(256) void prefilter_kernel(
        const float* __restrict__ conf,            // [B*P, C]
        unsigned int* __restrict__ cnt_g,          // [168]
        unsigned long long* __restrict__ cand_g) { // [168][CAP]
    __shared__ float tile[RPB * NUM_CLASSES];      // 43008 B
    const int r0 = blockIdx.x * RPB;
    const int t  = threadIdx.x;

    // coalesced float4 staging: 512*21 floats = 2688 float4
    {
        const float4* src4 = (const float4*)(conf + (long long)r0 * NUM_CLASSES);
        float4* dst4 = (float4*)tile;
        for (int i = t; i < (RPB * NUM_CLASSES) / 4; i += 256) dst4[i] = src4[i];
    }
    __syncthreads();

    for (int l = t; l < RPB; l += 256) {
        const int r = r0 + l;
        const int b = r / P_NUM;
        const int p = r - b * P_NUM;
        const float* row = &tile[l * NUM_CLASSES];
        #pragma unroll
        for (int c = 1; c < NUM_CLASSES; ++c) {
            float s = row[c];
            if (s > PRE_TH) {
                int bc = b * NUM_CLASSES + c;
                unsigned int pos = atomicAdd(&cnt_g[bc], 1u);
                if (pos < CAP) {
                    cand_g[(long long)bc * CAP + pos] =
                        ((unsigned long long)__float_as_uint(s) << 32)
                      | (unsigned long long)(0xFFFFFFFFu - (unsigned int)p);
                }
            }
        }
    }
}

// ---------------------------------------------------------------------------
// Kernel 2: per-(b,c) exact top-200 + greedy NMS.
// Fast path: candidates from global prefilter buffer (tiny).
// Fallback (never on this data): full strided scan with histogram threshold.
// ---------------------------------------------------------------------------
__global__ __launch_bounds__(256) void select_nms_kernel(
        const float* __restrict__ conf,       // [B*P, C]
        const float* __restrict__ loc,        // [B, P, 4]
        const float* __restrict__ prior,      // [P, 4]
        float* __restrict__ out,              // [B, C, TOPK, 5]
        int use_fast,
        const unsigned int* __restrict__ cnt_g,
        const unsigned long long* __restrict__ cand_g) {
    #pragma clang fp contract(off)

    const int c = blockIdx.x;
    const int b = blockIdx.y;
    const int t = threadIdx.x;
    const long long obase = ((long long)(b * NUM_CLASSES + c)) * (TOPK * 5);

    if (c == 0) {
        for (int e = t; e < TOPK * 5; e += 256) out[obase + e] = 0.0f;
        return;
    }

    __shared__ unsigned int hist[NBINS];                 // 16384 B
    __shared__ unsigned long long candA[CAP];            // 16384 B
    __shared__ unsigned long long cand2[CAP];            // 16384 B
    __shared__ float bx[TOPK][4];
    __shared__ float sc[TOPK];
    __shared__ float ar[TOPK];
    __shared__ unsigned long long msk[TOPK][4];
    __shared__ int keepi[TOPK];
    __shared__ unsigned int gsum[64];
    __shared__ int s_cnt2, s_tbin, s_nkeep;

    for (int i = t; i < NBINS; i += 256) hist[i] = 0u;
    if (t == 0) { s_cnt2 = 0; s_nkeep = 0; }
    __syncthreads();

    const int bc = b * NUM_CLASSES + c;
    const int n_pre = use_fast ? (int)cnt_g[bc] : 0;
    const bool fast = use_fast && (n_pre >= TOPK) && (n_pre <= CAP);

    if (fast) {
        // ---- load candidates, histogram over [PRE_TH, 1.0) -----------------
        const unsigned long long* src = cand_g + (long long)bc * CAP;
        const float hscale = (float)NBINS / (1.0f - PRE_TH);
        for (int i = t; i < n_pre; i += 256) {
            unsigned long long k = src[i];
            candA[i] = k;
            float s = __uint_as_float((unsigned int)(k >> 32));
            int bin = (int)((s - PRE_TH) * hscale);
            bin = min(max(bin, 0), NBINS - 1);
            atomicAdd(&hist[bin], 1u);
        }
        __syncthreads();
    } else {
        // ---- fallback: full strided histogram over [0,1) -------------------
        const float* src = conf + (long long)b * P_NUM * NUM_CLASSES + c;
        for (int p = t; p < P_NUM; p += 256) {
            float s = src[(long long)p * NUM_CLASSES];
            if (s > CONF_TH) {
                int bin = (int)(s * (float)NBINS);
                bin = min(max(bin, 0), NBINS - 1);
                atomicAdd(&hist[bin], 1u);
            }
        }
        __syncthreads();
    }

    // ---- find threshold bin: largest tbin with suffix-count >= TOPK --------
    if (t < 64) {
        unsigned int a = 0;
        #pragma unroll
        for (int i = 0; i < 64; ++i) a += hist[t * 64 + i];
        gsum[t] = a;
    }
    __syncthreads();
    if (t == 0) {
        int acc = 0;
        int g = 63;
        for (; g >= 0; --g) {
            if (acc + (int)gsum[g] >= TOPK) break;
            acc += (int)gsum[g];
        }
        int tbin = 0;
        if (g >= 0) {
            int bbase = g * 64;
            for (int bi = 63; bi >= 0; --bi) {
                acc += (int)hist[bbase + bi];
                if (acc >= TOPK) { tbin = bbase + bi; break; }
            }
        }
        s_tbin = tbin;
    }
    __syncthreads();
    const int tbin = s_tbin;

    // ---- collect candidates with bin >= tbin -------------------------------
    if (fast) {
        const float hscale = (float)NBINS / (1.0f - PRE_TH);
        for (int i = t; i < n_pre; i += 256) {
            unsigned long long k = candA[i];
            float s = __uint_as_float((unsigned int)(k >> 32));
            int bin = (int)((s - PRE_TH) * hscale);
            bin = min(max(bin, 0), NBINS - 1);
            if (bin >= tbin) {
                int pos = atomicAdd(&s_cnt2, 1);
                if (pos < CAP) cand2[pos] = k;
            }
        }
    } else {
        const float* src = conf + (long long)b * P_NUM * NUM_CLASSES + c;
        for (int p = t; p < P_NUM; p += 256) {
            float s = src[(long long)p * NUM_CLASSES];
            if (s > CONF_TH) {
                int bin = (int)(s * (float)NBINS);
                bin = min(max(bin, 0), NBINS - 1);
                if (bin >= tbin) {
                    int pos = atomicAdd(&s_cnt2, 1);
                    if (pos < CAP) {
                        cand2[pos] = ((unsigned long long)__float_as_uint(s) << 32)
                                   | (unsigned long long)(0xFFFFFFFFu - (unsigned int)p);
                    }
                }
            }
        }
    }
    __syncthreads();

    // ---- bitonic sort descending (score desc, index asc) -------------------
    int n2 = min(s_cnt2, CAP);
    int N = 256;
    while (N < n2) N <<= 1;
    for (int i = n2 + t; i < N; i += 256) cand2[i] = 0ULL;
    __syncthreads();
    for (int k = 2; k <= N; k <<= 1) {
        for (int j = k >> 1; j > 0; j >>= 1) {
            for (int i = t; i < N; i += 256) {
                int ixj = i ^ j;
                if (ixj > i) {
                    unsigned long long a = cand2[i], bb = cand2[ixj];
                    bool up = ((i & k) == 0);
                    if (up ? (a < bb) : (a > bb)) { cand2[i] = bb; cand2[ixj] = a; }
                }
            }
            __syncthreads();
        }
    }

    // ---- decode selected boxes --------------------------------------------
    const int nrows = min(n2, TOPK);
    if (t < nrows) {
        unsigned long long kk = cand2[t];
        float s = __uint_as_float((unsigned int)(kk >> 32));
        unsigned int p = 0xFFFFFFFFu - (unsigned int)kk;
        const float* lp = loc + ((long long)b * P_NUM + p) * 4;
        const float* pp = prior + (long long)p * 4;
        float l0 = lp[0], l1 = lp[1], l2 = lp[2], l3 = lp[3];
        float pcx = pp[0], pcy = pp[1], pw = pp[2], ph = pp[3];
        float cx = pcx + (l0 * 0.1f) * pw;
        float cy = pcy + (l1 * 0.1f) * ph;
        float w  = pw * expf(l2 * 0.2f);
        float h  = ph * expf(l3 * 0.2f);
        float x1 = cx - w * 0.5f;
        float y1 = cy - h * 0.5f;
        float x2 = x1 + w;
        float y2 = y1 + h;
        bx[t][0] = x1; bx[t][1] = y1; bx[t][2] = x2; bx[t][3] = y2;
        sc[t] = s;
        ar[t] = (x2 - x1) * (y2 - y1);
    }
    __syncthreads();

    // ---- pairwise IoU > thresh bitmask ------------------------------------
    int units = nrows * 4;
    for (int u = t; u < units; u += 256) {
        int i = u >> 2, w = u & 3;
        float ix1 = bx[i][0], iy1 = bx[i][1], ix2 = bx[i][2], iy2 = bx[i][3], ia = ar[i];
        unsigned long long m = 0ULL;
        int j0 = w * 64;
        int jend = min(64, nrows - j0);
        for (int jj = 0; jj < jend; ++jj) {
            int j = j0 + jj;
            float xx1 = fmaxf(ix1, bx[j][0]);
            float yy1 = fmaxf(iy1, bx[j][1]);
            float xx2 = fminf(ix2, bx[j][2]);
            float yy2 = fminf(iy2, bx[j][3]);
            float ww = fmaxf(xx2 - xx1, 0.0f);
            float hh = fmaxf(yy2 - yy1, 0.0f);
            float inter = ww * hh;
            float uni = (ar[j] - inter) + ia;     // numpy order: area_j - inter + area_i
            float iou = inter / uni;
            if (iou > NMS_TH) m |= (1ULL << jj);
        }
        msk[i][w] = m;
    }
    __syncthreads();

    // ---- greedy scan (serial, bitmask OR) ---------------------------------
    if (t == 0) {
        unsigned long long s0 = 0, s1 = 0, s2 = 0, s3 = 0;
        int nk = 0;
        for (int i = 0; i < nrows; ++i) {
            unsigned long long sw = (i < 64) ? s0 : (i < 128) ? s1 : (i < 192) ? s2 : s3;
            if ((sw >> (i & 63)) & 1ULL) continue;
            keepi[nk++] = i;
            s0 |= msk[i][0]; s1 |= msk[i][1]; s2 |= msk[i][2]; s3 |= msk[i][3];
        }
        s_nkeep = nk;
    }
    __syncthreads();

    // ---- write output (kept rows in pick order, zero padded) --------------
    int nk = s_nkeep;
    for (int e = t; e < TOPK * 5; e += 256) {
        int r = e / 5, comp = e - r * 5;
        float v = 0.0f;
        if (r < nk) {
            int i = keepi[r];
            v = (comp == 0) ? sc[i] : bx[i][comp - 1];
        }
        out[obase + e] = v;
    }
}

// ---------------------------------------------------------------------------
extern "C" void kernel_launch(void* const* d_in, const int* in_sizes, int n_in,
                              void* d_out, int out_size, void* d_ws, size_t ws_size,
                              hipStream_t stream) {
    const float* loc   = (const float*)d_in[0];
    const float* conf  = (const float*)d_in[1];
    const float* prior = (const float*)d_in[2];
    float* out = (float*)d_out;

    const size_t need = CAND_OFF + (size_t)B_NUM * NUM_CLASSES * CAP * 8;
    const int use_fast = (ws_size >= need) ? 1 : 0;
    unsigned int* cnt_g = (unsigned int*)d_ws;
    unsigned long long* cand_g = (unsigned long long*)((char*)d_ws + CAND_OFF);

    if (use_fast) {
        hipMemsetAsync(d_ws, 0, B_NUM * NUM_CLASSES * sizeof(unsigned int), stream);
        const int nblocks = (B_NUM * P_NUM) / RPB;   // 960000/512 = 1875
        prefilter_kernel<<<nblocks, 256, 0, stream>>>(conf, cnt_g, cand_g);
    }
    dim3 grid(NUM_CLASSES, B_NUM);
    select_nms_kernel<<<grid, 256, 0, stream>>>(conf, loc, prior, out, use_fast,
                                                cnt_g, cand_g);
}

// Round 3
// 205.702 us; speedup vs baseline: 4.2563x; 4.2563x over previous
//
#include <hip/hip_runtime.h>
#include <stdint.h>
#include <math.h>

#define NUM_CLASSES 21
#define TOPK 200
#define P_NUM 120000
#define B_NUM 8
#define NBINS 4096
#define CAP 2048
#define PRE_TH 0.99f
#define CONF_TH 0.05f
#define NMS_TH 0.3f

#define NBLK_PER_B 60
#define ROWS_PER_BLK (P_NUM / NBLK_PER_B)          // 2000
#define SEG_FLOATS (ROWS_PER_BLK * NUM_CLASSES)    // 42000
#define SLOT_CAP 64
#define NBLK (B_NUM * NBLK_PER_B)                  // 480

// ws layout: [0, NBLK*21*4) cnt_blk ; [64K, ...) cand_blk [NBLK][21][SLOT_CAP] u64
#define CAND_OFF 65536

// ---------------------------------------------------------------------------
// Kernel 1: wide prefilter, NO global atomics. Each block owns a 2000-row
// segment of one image; collects scores > PRE_TH into per-class LDS lists,
// then writes counts + items to its private global region.
// ---------------------------------------------------------------------------
__global__ __launch_bounds__(256) void prefilter_kernel(
        const float* __restrict__ conf,            // [B*P, C]
        unsigned int* __restrict__ cnt_blk,        // [NBLK][21]
        unsigned long long* __restrict__ cand_blk) // [NBLK][21][SLOT_CAP]
{
    __shared__ unsigned int scnt[NUM_CLASSES];
    __shared__ unsigned long long sbuf[NUM_CLASSES][SLOT_CAP];   // 10752 B
    const int blk = blockIdx.x;
    const int b   = blk / NBLK_PER_B;
    const int seg = blk - b * NBLK_PER_B;
    const int t   = threadIdx.x;

    if (t < NUM_CLASSES) scnt[t] = 0u;
    __syncthreads();

    const float* base = conf + ((long long)b * P_NUM + (long long)seg * ROWS_PER_BLK) * NUM_CLASSES;
    const float4* b4 = (const float4*)base;        // SEG_FLOATS % 4 == 0, aligned
    for (int i = t; i < SEG_FLOATS / 4; i += 256) {
        float4 v = b4[i];
        const int f0 = i * 4;
        #pragma unroll
        for (int j = 0; j < 4; ++j) {
            float s = (j == 0) ? v.x : (j == 1) ? v.y : (j == 2) ? v.z : v.w;
            if (s > PRE_TH) {
                int f = f0 + j;
                int r = f / NUM_CLASSES;           // compiler magic-mul
                int c = f - r * NUM_CLASSES;
                if (c != 0) {
                    unsigned int p = (unsigned int)(seg * ROWS_PER_BLK + r);
                    unsigned int pos = atomicAdd(&scnt[c], 1u);
                    if (pos < SLOT_CAP) {
                        sbuf[c][pos] = ((unsigned long long)__float_as_uint(s) << 32)
                                     | (unsigned long long)(0xFFFFFFFFu - p);
                    }
                }
            }
        }
    }
    __syncthreads();

    if (t < NUM_CLASSES) cnt_blk[blk * NUM_CLASSES + t] = scnt[t];
    for (int idx = t; idx < NUM_CLASSES * SLOT_CAP; idx += 256) {
        int c  = idx / SLOT_CAP;
        int sl = idx - c * SLOT_CAP;
        unsigned int n = scnt[c];
        if (sl < (int)(n < SLOT_CAP ? n : SLOT_CAP)) {
            cand_blk[((long long)blk * NUM_CLASSES + c) * SLOT_CAP + sl] = sbuf[c][sl];
        }
    }
}

// ---------------------------------------------------------------------------
// Kernel 2: per-(b,c) exact top-200 + greedy NMS.
// Fast path: gather candidates from prefilter segments (tiny, no atomics).
// Fallback (exactness guard, never triggers on this data): full strided scan.
// ---------------------------------------------------------------------------
__global__ __launch_bounds__(256) void select_nms_kernel(
        const float* __restrict__ conf,       // [B*P, C]
        const float* __restrict__ loc,        // [B, P, 4]
        const float* __restrict__ prior,      // [P, 4]
        float* __restrict__ out,              // [B, C, TOPK, 5]
        int use_fast,
        const unsigned int* __restrict__ cnt_blk,
        const unsigned long long* __restrict__ cand_blk) {
    #pragma clang fp contract(off)

    const int c = blockIdx.x;
    const int b = blockIdx.y;
    const int t = threadIdx.x;
    const long long obase = ((long long)(b * NUM_CLASSES + c)) * (TOPK * 5);

    if (c == 0) {
        for (int e = t; e < TOPK * 5; e += 256) out[obase + e] = 0.0f;
        return;
    }

    __shared__ unsigned int hist[NBINS];                 // 16384 B
    __shared__ unsigned long long candA[CAP];            // 16384 B
    __shared__ unsigned long long cand2[CAP];            // 16384 B
    __shared__ float bx[TOPK][4];
    __shared__ float sc[TOPK];
    __shared__ float ar[TOPK];
    __shared__ unsigned long long msk[TOPK][4];
    __shared__ int keepi[TOPK];
    __shared__ unsigned int gsum[64];
    __shared__ unsigned int bcnt[NBLK_PER_B];
    __shared__ unsigned int boff[NBLK_PER_B + 1];
    __shared__ int s_cnt2, s_tbin, s_nkeep, s_ok;

    for (int i = t; i < NBINS; i += 256) hist[i] = 0u;
    if (t == 0) { s_cnt2 = 0; s_nkeep = 0; s_ok = 0; }
    __syncthreads();

    // ---- gather prefiltered candidates -------------------------------------
    if (use_fast) {
        if (t < NBLK_PER_B) bcnt[t] = cnt_blk[(b * NBLK_PER_B + t) * NUM_CLASSES + c];
        __syncthreads();
        if (t == 0) {
            unsigned int acc = 0; int ok = 1;
            for (int i = 0; i < NBLK_PER_B; ++i) {
                boff[i] = acc;
                unsigned int n = bcnt[i];
                if (n > SLOT_CAP) ok = 0;
                acc += (n < SLOT_CAP ? n : SLOT_CAP);
            }
            boff[NBLK_PER_B] = acc;
            s_ok = (ok && acc >= TOPK && acc <= CAP) ? 1 : 0;
        }
        __syncthreads();
    }
    const bool fast = use_fast && s_ok;
    const int n_pre = fast ? (int)boff[NBLK_PER_B] : 0;

    if (fast) {
        // load candidates + histogram over [PRE_TH, 1.0)
        const float hscale = (float)NBINS / (1.0f - PRE_TH);
        for (int idx = t; idx < NBLK_PER_B * SLOT_CAP; idx += 256) {
            int sb = idx / SLOT_CAP;
            int sl = idx - sb * SLOT_CAP;
            unsigned int n = bcnt[sb];
            if (sl < (int)n) {
                unsigned long long k =
                    cand_blk[((long long)(b * NBLK_PER_B + sb) * NUM_CLASSES + c) * SLOT_CAP + sl];
                candA[boff[sb] + sl] = k;
                float s = __uint_as_float((unsigned int)(k >> 32));
                int bin = (int)((s - PRE_TH) * hscale);
                bin = min(max(bin, 0), NBINS - 1);
                atomicAdd(&hist[bin], 1u);
            }
        }
        __syncthreads();
    } else {
        // fallback: full strided histogram over [0,1)
        const float* src = conf + (long long)b * P_NUM * NUM_CLASSES + c;
        for (int p = t; p < P_NUM; p += 256) {
            float s = src[(long long)p * NUM_CLASSES];
            if (s > CONF_TH) {
                int bin = (int)(s * (float)NBINS);
                bin = min(max(bin, 0), NBINS - 1);
                atomicAdd(&hist[bin], 1u);
            }
        }
        __syncthreads();
    }

    // ---- find threshold bin: largest tbin with suffix-count >= TOPK --------
    if (t < 64) {
        unsigned int a = 0;
        #pragma unroll
        for (int i = 0; i < 64; ++i) a += hist[t * 64 + i];
        gsum[t] = a;
    }
    __syncthreads();
    if (t == 0) {
        int acc = 0;
        int g = 63;
        for (; g >= 0; --g) {
            if (acc + (int)gsum[g] >= TOPK) break;
            acc += (int)gsum[g];
        }
        int tbin = 0;
        if (g >= 0) {
            int bbase = g * 64;
            for (int bi = 63; bi >= 0; --bi) {
                acc += (int)hist[bbase + bi];
                if (acc >= TOPK) { tbin = bbase + bi; break; }
            }
        }
        s_tbin = tbin;
    }
    __syncthreads();
    const int tbin = s_tbin;

    // ---- compact candidates with bin >= tbin -------------------------------
    if (fast) {
        const float hscale = (float)NBINS / (1.0f - PRE_TH);
        for (int i = t; i < n_pre; i += 256) {
            unsigned long long k = candA[i];
            float s = __uint_as_float((unsigned int)(k >> 32));
            int bin = (int)((s - PRE_TH) * hscale);
            bin = min(max(bin, 0), NBINS - 1);
            if (bin >= tbin) {
                int pos = atomicAdd(&s_cnt2, 1);
                if (pos < CAP) cand2[pos] = k;
            }
        }
    } else {
        const float* src = conf + (long long)b * P_NUM * NUM_CLASSES + c;
        for (int p = t; p < P_NUM; p += 256) {
            float s = src[(long long)p * NUM_CLASSES];
            if (s > CONF_TH) {
                int bin = (int)(s * (float)NBINS);
                bin = min(max(bin, 0), NBINS - 1);
                if (bin >= tbin) {
                    int pos = atomicAdd(&s_cnt2, 1);
                    if (pos < CAP) {
                        cand2[pos] = ((unsigned long long)__float_as_uint(s) << 32)
                                   | (unsigned long long)(0xFFFFFFFFu - (unsigned int)p);
                    }
                }
            }
        }
    }
    __syncthreads();

    // ---- bitonic sort descending (score desc, index asc) -------------------
    int n2 = min(s_cnt2, CAP);
    int N = 256;
    while (N < n2) N <<= 1;
    for (int i = n2 + t; i < N; i += 256) cand2[i] = 0ULL;
    __syncthreads();
    for (int k = 2; k <= N; k <<= 1) {
        for (int j = k >> 1; j > 0; j >>= 1) {
            for (int i = t; i < N; i += 256) {
                int ixj = i ^ j;
                if (ixj > i) {
                    unsigned long long a = cand2[i], bb = cand2[ixj];
                    bool up = ((i & k) == 0);
                    if (up ? (a < bb) : (a > bb)) { cand2[i] = bb; cand2[ixj] = a; }
                }
            }
            __syncthreads();
        }
    }

    // ---- decode selected boxes --------------------------------------------
    const int nrows = min(n2, TOPK);
    if (t < nrows) {
        unsigned long long kk = cand2[t];
        float s = __uint_as_float((unsigned int)(kk >> 32));
        unsigned int p = 0xFFFFFFFFu - (unsigned int)kk;
        const float* lp = loc + ((long long)b * P_NUM + p) * 4;
        const float* pp = prior + (long long)p * 4;
        float l0 = lp[0], l1 = lp[1], l2 = lp[2], l3 = lp[3];
        float pcx = pp[0], pcy = pp[1], pw = pp[2], ph = pp[3];
        float cx = pcx + (l0 * 0.1f) * pw;
        float cy = pcy + (l1 * 0.1f) * ph;
        float w  = pw * expf(l2 * 0.2f);
        float h  = ph * expf(l3 * 0.2f);
        float x1 = cx - w * 0.5f;
        float y1 = cy - h * 0.5f;
        float x2 = x1 + w;
        float y2 = y1 + h;
        bx[t][0] = x1; bx[t][1] = y1; bx[t][2] = x2; bx[t][3] = y2;
        sc[t] = s;
        ar[t] = (x2 - x1) * (y2 - y1);
    }
    __syncthreads();

    // ---- pairwise IoU > thresh bitmask ------------------------------------
    int units = nrows * 4;
    for (int u = t; u < units; u += 256) {
        int i = u >> 2, w = u & 3;
        float ix1 = bx[i][0], iy1 = bx[i][1], ix2 = bx[i][2], iy2 = bx[i][3], ia = ar[i];
        unsigned long long m = 0ULL;
        int j0 = w * 64;
        int jend = min(64, nrows - j0);
        for (int jj = 0; jj < jend; ++jj) {
            int j = j0 + jj;
            float xx1 = fmaxf(ix1, bx[j][0]);
            float yy1 = fmaxf(iy1, bx[j][1]);
            float xx2 = fminf(ix2, bx[j][2]);
            float yy2 = fminf(iy2, bx[j][3]);
            float ww = fmaxf(xx2 - xx1, 0.0f);
            float hh = fmaxf(yy2 - yy1, 0.0f);
            float inter = ww * hh;
            float uni = (ar[j] - inter) + ia;     // numpy order: area_j - inter + area_i
            float iou = inter / uni;
            if (iou > NMS_TH) m |= (1ULL << jj);
        }
        msk[i][w] = m;
    }
    __syncthreads();

    // ---- greedy scan (serial, bitmask OR) ---------------------------------
    if (t == 0) {
        unsigned long long s0 = 0, s1 = 0, s2 = 0, s3 = 0;
        int nk = 0;
        for (int i = 0; i < nrows; ++i) {
            unsigned long long sw = (i < 64) ? s0 : (i < 128) ? s1 : (i < 192) ? s2 : s3;
            if ((sw >> (i & 63)) & 1ULL) continue;
            keepi[nk++] = i;
            s0 |= msk[i][0]; s1 |= msk[i][1]; s2 |= msk[i][2]; s3 |= msk[i][3];
        }
        s_nkeep = nk;
    }
    __syncthreads();

    // ---- write output (kept rows in pick order, zero padded) --------------
    int nk = s_nkeep;
    for (int e = t; e < TOPK * 5; e += 256) {
        int r = e / 5, comp = e - r * 5;
        float v = 0.0f;
        if (r < nk) {
            int i = keepi[r];
            v = (comp == 0) ? sc[i] : bx[i][comp - 1];
        }
        out[obase + e] = v;
    }
}

// ---------------------------------------------------------------------------
extern "C" void kernel_launch(void* const* d_in, const int* in_sizes, int n_in,
                              void* d_out, int out_size, void* d_ws, size_t ws_size,
                              hipStream_t stream) {
    const float* loc   = (const float*)d_in[0];
    const float* conf  = (const float*)d_in[1];
    const float* prior = (const float*)d_in[2];
    float* out = (float*)d_out;

    const size_t need = CAND_OFF + (size_t)NBLK * NUM_CLASSES * SLOT_CAP * 8;
    const int use_fast = (ws_size >= need) ? 1 : 0;
    unsigned int* cnt_blk = (unsigned int*)d_ws;
    unsigned long long* cand_blk = (unsigned long long*)((char*)d_ws + CAND_OFF);

    if (use_fast) {
        prefilter_kernel<<<NBLK, 256, 0, stream>>>(conf, cnt_blk, cand_blk);
    }
    dim3 grid(NUM_CLASSES, B_NUM);
    select_nms_kernel<<<grid, 256, 0, stream>>>(conf, loc, prior, out, use_fast,
                                                cnt_blk, cand_blk);
}

// Round 4
// 185.884 us; speedup vs baseline: 4.7101x; 1.1066x over previous
//
#include <hip/hip_runtime.h>
#include <stdint.h>
#include <math.h>

#define NUM_CLASSES 21
#define TOPK 200
#define P_NUM 120000
#define B_NUM 8
#define NBINS 4096
#define CAP 2048
#define PRE_TH 0.9965f
#define CONF_TH 0.05f
#define NMS_TH 0.3f

#define NBLK_PER_B 120
#define ROWS_PER_BLK (P_NUM / NBLK_PER_B)          // 1000
#define SEG_FLOATS (ROWS_PER_BLK * NUM_CLASSES)    // 21000
#define SEG_F4 (SEG_FLOATS / 4)                    // 5250
#define SLOT_CAP 16
#define NBLK (B_NUM * NBLK_PER_B)                  // 960

// ws layout: [0, NBLK*21*4 = 80640) cnt_blk ; [131072, +2.58M) cand_blk
#define CAND_OFF 131072

// ---------------------------------------------------------------------------
// Kernel 1: wide prefilter, no global atomics. Each block owns a 1000-row
// segment of one image; collects scores > PRE_TH into per-class LDS lists,
// then writes counts + items to its private global region.
// ---------------------------------------------------------------------------
__global__ __launch_bounds__(256) void prefilter_kernel(
        const float* __restrict__ conf,            // [B*P, C]
        unsigned int* __restrict__ cnt_blk,        // [NBLK][21]
        unsigned long long* __restrict__ cand_blk) // [NBLK][21][SLOT_CAP]
{
    __shared__ unsigned int scnt[NUM_CLASSES];
    __shared__ unsigned long long sbuf[NUM_CLASSES][SLOT_CAP];   // 2688 B
    const int blk = blockIdx.x;
    const int b   = blk / NBLK_PER_B;
    const int seg = blk - b * NBLK_PER_B;
    const int t   = threadIdx.x;

    if (t < NUM_CLASSES) scnt[t] = 0u;
    __syncthreads();

    const float* base = conf + ((long long)b * P_NUM + (long long)seg * ROWS_PER_BLK) * NUM_CLASSES;
    const float4* b4 = (const float4*)base;        // 84000 B segment, 16B aligned
    #pragma unroll 4
    for (int i = t; i < SEG_F4; i += 256) {
        float4 v = b4[i];
        float m = fmaxf(fmaxf(v.x, v.y), fmaxf(v.z, v.w));
        if (m > PRE_TH) {
            const int f0 = i * 4;
            #pragma unroll
            for (int j = 0; j < 4; ++j) {
                float s = (j == 0) ? v.x : (j == 1) ? v.y : (j == 2) ? v.z : v.w;
                if (s > PRE_TH) {
                    int f = f0 + j;
                    int r = f / NUM_CLASSES;
                    int c = f - r * NUM_CLASSES;
                    if (c != 0) {
                        unsigned int p = (unsigned int)(seg * ROWS_PER_BLK + r);
                        unsigned int pos = atomicAdd(&scnt[c], 1u);
                        if (pos < SLOT_CAP) {
                            sbuf[c][pos] = ((unsigned long long)__float_as_uint(s) << 32)
                                         | (unsigned long long)(0xFFFFFFFFu - p);
                        }
                    }
                }
            }
        }
    }
    __syncthreads();

    if (t < NUM_CLASSES) cnt_blk[blk * NUM_CLASSES + t] = scnt[t];
    for (int idx = t; idx < NUM_CLASSES * SLOT_CAP; idx += 256) {
        int c  = idx >> 4;
        int sl = idx & (SLOT_CAP - 1);
        unsigned int n = scnt[c];
        if (sl < (int)(n < SLOT_CAP ? n : SLOT_CAP)) {
            cand_blk[((long long)blk * NUM_CLASSES + c) * SLOT_CAP + sl] = sbuf[c][sl];
        }
    }
}

// ---------------------------------------------------------------------------
// Kernel 2: per-(b,c) exact top-200 + greedy NMS. Fast path: gather ~420
// prefiltered candidates, O(M^2) rank-sort (exact, unique keys). Fallback
// (guard-protected, not expected to trigger): full strided histogram scan.
// ---------------------------------------------------------------------------
__global__ __launch_bounds__(512) void select_nms_kernel(
        const float* __restrict__ conf,       // [B*P, C]
        const float* __restrict__ loc,        // [B, P, 4]
        const float* __restrict__ prior,      // [P, 4]
        float* __restrict__ out,              // [B, C, TOPK, 5]
        int use_fast,
        const unsigned int* __restrict__ cnt_blk,
        const unsigned long long* __restrict__ cand_blk) {
    #pragma clang fp contract(off)

    const int c = blockIdx.x;
    const int b = blockIdx.y;
    const int t = threadIdx.x;
    const long long obase = ((long long)(b * NUM_CLASSES + c)) * (TOPK * 5);

    if (c == 0) {
        for (int e = t; e < TOPK * 5; e += 512) out[obase + e] = 0.0f;
        return;
    }

    __shared__ unsigned long long candA[CAP];            // 16384 B
    __shared__ unsigned int hist[NBINS];                 // 16384 B (fallback only)
    __shared__ unsigned long long sorted_k[TOPK];        // 1600 B
    __shared__ float bx[TOPK][4];
    __shared__ float sc[TOPK];
    __shared__ float ar[TOPK];
    __shared__ unsigned long long msk[TOPK][4];
    __shared__ int keepi[TOPK];
    __shared__ unsigned int gsum[64];
    __shared__ unsigned int bcnt[NBLK_PER_B];
    __shared__ unsigned int boff[NBLK_PER_B + 1];
    __shared__ int s_cnt2, s_tbin, s_nkeep, s_ok;

    if (t == 0) { s_cnt2 = 0; s_nkeep = 0; s_ok = 0; }
    if (use_fast && t < NBLK_PER_B)
        bcnt[t] = cnt_blk[(b * NBLK_PER_B + t) * NUM_CLASSES + c];
    __syncthreads();
    if (use_fast && t == 0) {
        unsigned int acc = 0; int ok = 1;
        for (int i = 0; i < NBLK_PER_B; ++i) {
            boff[i] = acc;
            unsigned int n = bcnt[i];
            if (n > SLOT_CAP) ok = 0;
            acc += (n < SLOT_CAP ? n : SLOT_CAP);
        }
        boff[NBLK_PER_B] = acc;
        s_ok = (ok && acc >= TOPK && acc <= CAP) ? 1 : 0;
    }
    __syncthreads();

    const bool fast = use_fast && s_ok;
    int M;

    if (fast) {
        M = (int)boff[NBLK_PER_B];
        for (int idx = t; idx < NBLK_PER_B * SLOT_CAP; idx += 512) {
            int sb = idx >> 4;
            int sl = idx & (SLOT_CAP - 1);
            if (sl < (int)bcnt[sb]) {
                candA[boff[sb] + sl] =
                    cand_blk[((long long)(b * NBLK_PER_B + sb) * NUM_CLASSES + c) * SLOT_CAP + sl];
            }
        }
        __syncthreads();
    } else {
        // ---- fallback: full strided scan + histogram threshold -------------
        for (int i = t; i < NBINS; i += 512) hist[i] = 0u;
        __syncthreads();
        const float* src = conf + (long long)b * P_NUM * NUM_CLASSES + c;
        for (int p = t; p < P_NUM; p += 512) {
            float s = src[(long long)p * NUM_CLASSES];
            if (s > CONF_TH) {
                int bin = (int)(s * (float)NBINS);
                bin = min(max(bin, 0), NBINS - 1);
                atomicAdd(&hist[bin], 1u);
            }
        }
        __syncthreads();
        if (t < 64) {
            unsigned int a = 0;
            #pragma unroll
            for (int i = 0; i < 64; ++i) a += hist[t * 64 + i];
            gsum[t] = a;
        }
        __syncthreads();
        if (t == 0) {
            int acc = 0;
            int g = 63;
            for (; g >= 0; --g) {
                if (acc + (int)gsum[g] >= TOPK) break;
                acc += (int)gsum[g];
            }
            int tbin = 0;
            if (g >= 0) {
                int bbase = g * 64;
                for (int bi = 63; bi >= 0; --bi) {
                    acc += (int)hist[bbase + bi];
                    if (acc >= TOPK) { tbin = bbase + bi; break; }
                }
            }
            s_tbin = tbin;
        }
        __syncthreads();
        const int tbin = s_tbin;
        for (int p = t; p < P_NUM; p += 512) {
            float s = src[(long long)p * NUM_CLASSES];
            if (s > CONF_TH) {
                int bin = (int)(s * (float)NBINS);
                bin = min(max(bin, 0), NBINS - 1);
                if (bin >= tbin) {
                    int pos = atomicAdd(&s_cnt2, 1);
                    if (pos < CAP) {
                        candA[pos] = ((unsigned long long)__float_as_uint(s) << 32)
                                   | (unsigned long long)(0xFFFFFFFFu - (unsigned int)p);
                    }
                }
            }
        }
        __syncthreads();
        M = min(s_cnt2, CAP);
    }

    // ---- rank-sort: exact top-200 (keys unique: score_bits desc, idx asc) --
    {
        unsigned long long key[CAP / 512];
        int rnk[CAP / 512];
        #pragma unroll
        for (int k = 0; k < CAP / 512; ++k) {
            int idx = t + k * 512;
            key[k] = (idx < M) ? candA[idx] : 0ULL;
            rnk[k] = 0;
        }
        #pragma unroll 4
        for (int j = 0; j < M; ++j) {
            unsigned long long bj = candA[j];     // LDS broadcast
            #pragma unroll
            for (int k = 0; k < CAP / 512; ++k) rnk[k] += (bj > key[k]) ? 1 : 0;
        }
        #pragma unroll
        for (int k = 0; k < CAP / 512; ++k) {
            int idx = t + k * 512;
            if (idx < M && rnk[k] < TOPK) sorted_k[rnk[k]] = key[k];
        }
    }
    __syncthreads();

    // ---- decode selected boxes --------------------------------------------
    const int nrows = min(M, TOPK);
    if (t < nrows) {
        unsigned long long kk = sorted_k[t];
        float s = __uint_as_float((unsigned int)(kk >> 32));
        unsigned int p = 0xFFFFFFFFu - (unsigned int)kk;
        const float* lp = loc + ((long long)b * P_NUM + p) * 4;
        const float* pp = prior + (long long)p * 4;
        float l0 = lp[0], l1 = lp[1], l2 = lp[2], l3 = lp[3];
        float pcx = pp[0], pcy = pp[1], pw = pp[2], ph = pp[3];
        float cx = pcx + (l0 * 0.1f) * pw;
        float cy = pcy + (l1 * 0.1f) * ph;
        float w  = pw * expf(l2 * 0.2f);
        float h  = ph * expf(l3 * 0.2f);
        float x1 = cx - w * 0.5f;
        float y1 = cy - h * 0.5f;
        float x2 = x1 + w;
        float y2 = y1 + h;
        bx[t][0] = x1; bx[t][1] = y1; bx[t][2] = x2; bx[t][3] = y2;
        sc[t] = s;
        ar[t] = (x2 - x1) * (y2 - y1);
    }
    __syncthreads();

    // ---- pairwise IoU > thresh bitmask ------------------------------------
    int units = nrows * 4;
    for (int u = t; u < units; u += 512) {
        int i = u >> 2, w = u & 3;
        float ix1 = bx[i][0], iy1 = bx[i][1], ix2 = bx[i][2], iy2 = bx[i][3], ia = ar[i];
        unsigned long long m = 0ULL;
        int j0 = w * 64;
        int jend = min(64, nrows - j0);
        for (int jj = 0; jj < jend; ++jj) {
            int j = j0 + jj;
            float xx1 = fmaxf(ix1, bx[j][0]);
            float yy1 = fmaxf(iy1, bx[j][1]);
            float xx2 = fminf(ix2, bx[j][2]);
            float yy2 = fminf(iy2, bx[j][3]);
            float ww = fmaxf(xx2 - xx1, 0.0f);
            float hh = fmaxf(yy2 - yy1, 0.0f);
            float inter = ww * hh;
            float uni = (ar[j] - inter) + ia;     // numpy order: area_j - inter + area_i
            float iou = inter / uni;
            if (iou > NMS_TH) m |= (1ULL << jj);
        }
        msk[i][w] = m;
    }
    __syncthreads();

    // ---- greedy scan: ffs over remaining bitmask (iters = #keeps) ----------
    if (t == 0) {
        unsigned long long r0, r1, r2, r3;
        {
            int n0 = min(max(nrows -   0, 0), 64);
            int n1 = min(max(nrows -  64, 0), 64);
            int n2 = min(max(nrows - 128, 0), 64);
            int n3 = min(max(nrows - 192, 0), 64);
            r0 = (n0 == 64) ? ~0ULL : ((1ULL << n0) - 1ULL);
            r1 = (n1 == 64) ? ~0ULL : ((1ULL << n1) - 1ULL);
            r2 = (n2 == 64) ? ~0ULL : ((1ULL << n2) - 1ULL);
            r3 = (n3 == 64) ? ~0ULL : ((1ULL << n3) - 1ULL);
        }
        int nk = 0;
        for (;;) {
            int i;
            if      (r0) i =       __builtin_ctzll(r0);
            else if (r1) i =  64 + __builtin_ctzll(r1);
            else if (r2) i = 128 + __builtin_ctzll(r2);
            else if (r3) i = 192 + __builtin_ctzll(r3);
            else break;
            keepi[nk++] = i;
            unsigned long long m0 = msk[i][0], m1 = msk[i][1],
                               m2 = msk[i][2], m3 = msk[i][3];
            // clear self explicitly (diagonal is set only when area > 0)
            if      (i < 64)  m0 |= (1ULL << i);
            else if (i < 128) m1 |= (1ULL << (i - 64));
            else if (i < 192) m2 |= (1ULL << (i - 128));
            else              m3 |= (1ULL << (i - 192));
            r0 &= ~m0; r1 &= ~m1; r2 &= ~m2; r3 &= ~m3;
        }
        s_nkeep = nk;
    }
    __syncthreads();

    // ---- write output (kept rows in pick order, zero padded) --------------
    int nk = s_nkeep;
    for (int e = t; e < TOPK * 5; e += 512) {
        int r = e / 5, comp = e - r * 5;
        float v = 0.0f;
        if (r < nk) {
            int i = keepi[r];
            v = (comp == 0) ? sc[i] : bx[i][comp - 1];
        }
        out[obase + e] = v;
    }
}

// ---------------------------------------------------------------------------
extern "C" void kernel_launch(void* const* d_in, const int* in_sizes, int n_in,
                              void* d_out, int out_size, void* d_ws, size_t ws_size,
                              hipStream_t stream) {
    const float* loc   = (const float*)d_in[0];
    const float* conf  = (const float*)d_in[1];
    const float* prior = (const float*)d_in[2];
    float* out = (float*)d_out;

    const size_t need = CAND_OFF + (size_t)NBLK * NUM_CLASSES * SLOT_CAP * 8;  // ~2.7 MB
    const int use_fast = (ws_size >= need) ? 1 : 0;
    unsigned int* cnt_blk = (unsigned int*)d_ws;
    unsigned long long* cand_blk = (unsigned long long*)((char*)d_ws + CAND_OFF);

    if (use_fast) {
        prefilter_kernel<<<NBLK, 256, 0, stream>>>(conf, cnt_blk, cand_blk);
    }
    dim3 grid(NUM_CLASSES, B_NUM);
    select_nms_kernel<<<grid, 512, 0, stream>>>(conf, loc, prior, out, use_fast,
                                                cnt_blk, cand_blk);
}